// Round 17
// baseline (2586.356 us; speedup 1.0000x reference)
//
#include <hip/hip_runtime.h>

#define BB 64
#define TXX 512
#define DD 64
#define HH 1024
#define UU 512
#define TYY 16
#define G4 4096

using u16 = unsigned short;
typedef __attribute__((ext_vector_type(8))) short short8;
typedef __attribute__((ext_vector_type(4))) float f32x4;

__device__ __forceinline__ float bf2f(u16 v){ return __uint_as_float(((unsigned)v)<<16); }
__device__ __forceinline__ u16 f2bf(float f){
  unsigned u = __float_as_uint(f);
  u += 0x7FFF + ((u>>16)&1);
  return (u16)(u>>16);
}
__device__ __forceinline__ float sigm(float x){
  x = fminf(fmaxf(x,-30.f),30.f);
  return 1.f/(1.f+__expf(-x));
}
__device__ __forceinline__ float tanhfast(float x){
  x = fminf(fmaxf(x,-15.f),15.f);
  float e = __expf(2.f*x);
  return (e-1.f)/(e+1.f);
}

__device__ __forceinline__ unsigned long long tr16(unsigned addr){
  unsigned long long r;
  asm volatile("ds_read_b64_tr_b16 %0, %1" : "=v"(r) : "v"(addr));
  return r;
}

// LLC-coherent (cross-XCD) accesses: sc0 sc1 bypass L1/L2
__device__ __forceinline__ short8 load16_sc(const short8* p){
  short8 r;
  asm volatile("global_load_dwordx4 %0, %1, off sc0 sc1" : "=v"(r) : "v"(p) : "memory");
  return r;
}
__device__ __forceinline__ void store16_sc(void* p, short8 v){
  asm volatile("global_store_dwordx4 %0, %1, off sc0 sc1" :: "v"(p), "v"(v) : "memory");
}

// ---------------- persistent encoder (256 blocks, flag dataflow) -------------
// 256 blocks = 4 b-groups x 64 z-groups (16 h-cols each); 512 thr = 8 waves
// (K slice 128 each). h exchange via yencT (sc0sc1), relaxed per-producer
// flags; consumer wave polls its 8 producers.
// Gate threads: gb = tid&15 (bank-conflict-free zex reads), ghc = (tid>>4)&15.
__global__ __launch_bounds__(512, 2) void enc_persist(
    const float* __restrict__ x, const float* __restrict__ enc_k_,
    const float* __restrict__ enc_rk_, const float* __restrict__ enc_b_,
    u16* __restrict__ yencT, u16* __restrict__ hdec,
    float* __restrict__ cdec, u16* __restrict__ AdecA, unsigned* __restrict__ flags)
{
  extern __shared__ char smem[];
  float* zex = (float*)(smem + 32768);            // 8 x 1088 floats = 34816 B
  u16* hbou = (u16*)(smem + 32768 + 34816);       // 512 B
  const int tid = threadIdx.x, bid = blockIdx.x;
  const int l = tid & 63, w = tid >> 6;
  const int c = l & 15, koct = l >> 4;
  const int bg = bid & 3;
  const int zg = bid >> 2;                        // 0..63, 16 h-cols each

  short8 bR[16];
  #pragma unroll
  for (int kk=0; kk<4; ++kk){
    #pragma unroll
    for (int nt=0; nt<4; ++nt){
      short8 f;
      #pragma unroll
      for (int i=0; i<8; ++i){
        int k = w*128 + kk*32 + ((i<4) ? (koct*4+i) : (16 + koct*4 + (i-4)));
        int gcol = nt*1024 + zg*16 + c;
        f[i] = (short)f2bf(enc_rk_[(size_t)k*G4 + gcol]);
      }
      bR[kk*4+nt] = f;
    }
  }
  short8 bK[4];
  if (w < 2){
    #pragma unroll
    for (int nt=0; nt<4; ++nt){
      short8 f;
      #pragma unroll
      for (int i=0; i<8; ++i){
        int gcol = nt*1024 + zg*16 + c;
        f[i] = (short)f2bf(enc_k_[(size_t)(w*32 + koct*8 + i)*G4 + gcol]);
      }
      bK[nt] = f;
    }
  }
  // gate thread (tid<256): gb fastest-varying -> zex reads 2-way (free)
  const int gb = tid & 15, ghc = (tid >> 4) & 15;
  float bz[4];
  #pragma unroll
  for (int g4=0; g4<4; ++g4) bz[g4] = enc_b_[g4*1024 + zg*16 + ghc];
  float creg = 0.f;

  const unsigned ldsbase = (unsigned)(size_t)(void*)smem;

  for (int t=0; t<TXX; ++t){
    f32x4 acc[4];
    #pragma unroll
    for (int nt=0; nt<4; ++nt) acc[nt] = (f32x4){0.f,0.f,0.f,0.f};
    if (w < 2){
      const float* xp = x + (size_t)(bg*16 + c)*(TXX*DD) + (size_t)t*DD + w*32 + koct*8;
      float4 v0 = *(const float4*)(xp);
      float4 v1 = *(const float4*)(xp+4);
      short8 ax;
      ax[0]=(short)f2bf(v0.x); ax[1]=(short)f2bf(v0.y);
      ax[2]=(short)f2bf(v0.z); ax[3]=(short)f2bf(v0.w);
      ax[4]=(short)f2bf(v1.x); ax[5]=(short)f2bf(v1.y);
      ax[6]=(short)f2bf(v1.z); ax[7]=(short)f2bf(v1.w);
      #pragma unroll
      for (int nt=0; nt<4; ++nt)
        acc[nt] = __builtin_amdgcn_mfma_f32_16x16x32_bf16(ax, bK[nt], acc[nt], 0,0,0);
    }
    if (t > 0){
      // poll this wave's 8 producers (zg = w*8 .. w*8+7 of same bg)
      if (l < 8){
        const unsigned* fp = flags + ((w*8 + l)*4 + bg)*8;
        while (__hip_atomic_load(fp, __ATOMIC_RELAXED, __HIP_MEMORY_SCOPE_AGENT) < (unsigned)t)
          __builtin_amdgcn_s_sleep(1);
      }
      __builtin_amdgcn_sched_barrier(0);
      const short8* src = (const short8*)(yencT + ((size_t)((t-1)*4 + bg))*16384 + w*2048);
      short8 v0 = load16_sc(src + 0*64 + l);
      short8 v1 = load16_sc(src + 1*64 + l);
      short8 v2 = load16_sc(src + 2*64 + l);
      short8 v3 = load16_sc(src + 3*64 + l);
      asm volatile("s_waitcnt vmcnt(0)" ::: "memory");
      short8* dst = (short8*)(smem + w*4096);
      dst[0*64+l]=v0; dst[1*64+l]=v1; dst[2*64+l]=v2; dst[3*64+l]=v3;
      asm volatile("s_waitcnt lgkmcnt(0)" ::: "memory");
      unsigned a = ldsbase + (unsigned)(w*4096 + l*8);
      unsigned long long r0,r1,r2,r3,r4,r5,r6,r7;
      r0=tr16(a);      r1=tr16(a+512);
      r2=tr16(a+1024); r3=tr16(a+1536);
      r4=tr16(a+2048); r5=tr16(a+2560);
      r6=tr16(a+3072); r7=tr16(a+3584);
      asm volatile("s_waitcnt lgkmcnt(0)" ::: "memory");
      __builtin_amdgcn_sched_barrier(0);
      union { unsigned long long q[2]; short8 s; } u;
      u.q[0]=r0; u.q[1]=r1;
      #pragma unroll
      for (int nt=0; nt<4; ++nt) acc[nt] = __builtin_amdgcn_mfma_f32_16x16x32_bf16(u.s, bR[0+nt], acc[nt], 0,0,0);
      u.q[0]=r2; u.q[1]=r3;
      #pragma unroll
      for (int nt=0; nt<4; ++nt) acc[nt] = __builtin_amdgcn_mfma_f32_16x16x32_bf16(u.s, bR[4+nt], acc[nt], 0,0,0);
      u.q[0]=r4; u.q[1]=r5;
      #pragma unroll
      for (int nt=0; nt<4; ++nt) acc[nt] = __builtin_amdgcn_mfma_f32_16x16x32_bf16(u.s, bR[8+nt], acc[nt], 0,0,0);
      u.q[0]=r6; u.q[1]=r7;
      #pragma unroll
      for (int nt=0; nt<4; ++nt) acc[nt] = __builtin_amdgcn_mfma_f32_16x16x32_bf16(u.s, bR[12+nt], acc[nt], 0,0,0);
    }
    #pragma unroll
    for (int nt=0; nt<4; ++nt){
      #pragma unroll
      for (int j=0; j<4; ++j)
        zex[w*1088 + (koct*4+j)*68 + nt*16 + c] = acc[nt][j];
    }
    __syncthreads();
    if (tid < 256){
      float zsum[4];
      #pragma unroll
      for (int g4=0; g4<4; ++g4){
        float s2 = zex[gb*68 + g4*16 + ghc];
        #pragma unroll
        for (int ww=1; ww<8; ++ww) s2 += zex[ww*1088 + gb*68 + g4*16 + ghc];
        zsum[g4] = s2 + bz[g4];
      }
      float cnew = sigm(zsum[1])*creg + sigm(zsum[0])*tanhfast(zsum[2]);
      float hnew = sigm(zsum[3])*tanhfast(cnew);
      creg = cnew;
      u16 hb = f2bf(hnew);
      hbou[ghc*16 + gb] = hb;
      if (t == TXX-1){
        int bglob = bg*16 + gb;
        int col = zg*16 + ghc;
        hdec[(size_t)bglob*HH + col] = hb;
        cdec[(size_t)col*BB + bglob] = cnew;
        AdecA[(size_t)bglob*2080 + 1025 + col] = hb;
      }
    }
    __syncthreads();   // hbou complete
    if (tid < 32){
      short8 hv = *(const short8*)(hbou + tid*8);
      store16_sc(yencT + ((size_t)(t*4 + bg)*1024 + zg*16)*16 + tid*8, hv);
    }
    asm volatile("s_waitcnt vmcnt(0)" ::: "memory");
    if (tid == 0)
      __hip_atomic_store(flags + (zg*4 + bg)*8, (unsigned)(t+1),
                         __ATOMIC_RELAXED, __HIP_MEMORY_SCOPE_AGENT);
  }
}

// ---------------- Eenc = y_enc @ w1b[:H] + b1 (bf16 out, MFMA) ---------------
__global__ __launch_bounds__(256) void eenc_mfma(
    const u16* __restrict__ yencT, const u16* __restrict__ w1b,
    const float* __restrict__ b1, u16* __restrict__ eenc)
{
  __shared__ u16 As[4096];
  __shared__ u16 Bs[64*40];
  const int tid = threadIdx.x;
  const int l = tid&63, wm = tid>>6;
  const int c = l&15, koct = l>>4;
  const int t0 = blockIdx.x*2, n0 = blockIdx.y*64;
  const unsigned ab = (unsigned)(size_t)(void*)As;
  f32x4 acc[2][4];
  #pragma unroll
  for (int a=0;a<2;++a)
    #pragma unroll
    for (int b=0;b<4;++b) acc[a][b] = (f32x4){0.f,0.f,0.f,0.f};

  for (int k0=0; k0<HH; k0+=32){
    #pragma unroll
    for (int p=0; p<2; ++p){
      int e = p*256 + tid;
      int sub = e>>6, w16 = e&63;
      const u16* gsrc = yencT + ((size_t)((t0 + (sub>>2))*4 + (sub&3))*1024 + k0)*16 + w16*8;
      *(short8*)((char*)As + e*16) = *(const short8*)gsrc;
    }
    #pragma unroll
    for (int p=0; p<8; ++p){
      int e = p*256 + tid;
      int kk = e>>6, col = e&63;
      int k2 = kk & 15;
      int slot = (k2>>2)*8 + ((kk&16)?4:0) + (k2&3);
      Bs[col*40 + slot] = w1b[(size_t)(k0+kk)*UU + n0 + col];
    }
    __syncthreads();
    unsigned long long r00 = tr16(ab + wm*1024 + l*8);
    unsigned long long r01 = tr16(ab + wm*1024 + 512 + l*8);
    unsigned long long r10 = tr16(ab + (wm+4)*1024 + l*8);
    unsigned long long r11 = tr16(ab + (wm+4)*1024 + 512 + l*8);
    asm volatile("s_waitcnt lgkmcnt(0)" ::: "memory");
    __builtin_amdgcn_sched_barrier(0);
    union { unsigned long long q[2]; short8 s; } u0, u1;
    u0.q[0]=r00; u0.q[1]=r01;
    u1.q[0]=r10; u1.q[1]=r11;
    #pragma unroll
    for (int nt=0; nt<4; ++nt){
      short8 bf = *(const short8*)((const char*)Bs + (nt*16+c)*80 + koct*16);
      acc[0][nt] = __builtin_amdgcn_mfma_f32_16x16x32_bf16(u0.s, bf, acc[0][nt], 0,0,0);
      acc[1][nt] = __builtin_amdgcn_mfma_f32_16x16x32_bf16(u1.s, bf, acc[1][nt], 0,0,0);
    }
    __syncthreads();
  }
  float sbn[4];
  #pragma unroll
  for (int nt=0; nt<4; ++nt) sbn[nt] = b1[n0 + nt*16 + c];
  #pragma unroll
  for (int s=0; s<2; ++s){
    int sub = wm + s*4;
    int t = t0 + (sub>>2), g = sub&3;
    #pragma unroll
    for (int nt=0; nt<4; ++nt){
      #pragma unroll
      for (int j=0; j<4; ++j){
        int b = g*16 + koct*4 + j;
        eenc[((size_t)b*TXX + t)*UU + n0 + nt*16 + c] = f2bf(acc[s][nt][j] + sbn[nt]);
      }
    }
  }
}

// ---------------- hW = h @ w1b[H:] (fallback, LDS gather) --------------------
__global__ __launch_bounds__(256) void hw_mfma(
    const u16* __restrict__ hdec, const u16* __restrict__ w1b,
    float* __restrict__ hW)
{
  extern __shared__ char smem[];
  u16* As = (u16*)smem;
  u16* Ws = (u16*)(smem + 66560);
  const int tid = threadIdx.x;
  const int l = tid&63, w = tid>>6;
  const int c = l&15, koct = l>>4;
  const int u0 = blockIdx.x*16;
  f32x4 acc = {0.f,0.f,0.f,0.f};
  for (int ch=0; ch<2; ++ch){
    #pragma unroll
    for (int p=0; p<16; ++p){
      int e = p*256 + tid;
      int row = e>>6, k16 = e&63;
      *(short8*)((char*)As + row*1040 + k16*16) =
        *(const short8*)(hdec + (size_t)row*HH + ch*512 + k16*8);
    }
    #pragma unroll
    for (int p=0; p<32; ++p){
      int e = p*256 + tid;
      int kk = e>>4, cc = e&15;
      Ws[kk*19 + cc] = w1b[(size_t)(HH + ch*512 + kk)*UU + u0 + cc];
    }
    __syncthreads();
    #pragma unroll
    for (int s=0; s<16; ++s){
      short8 af = *(const short8*)((const char*)As + (w*16+c)*1040 + s*64 + koct*16);
      short8 bf;
      #pragma unroll
      for (int i=0; i<8; ++i) bf[i] = (short)Ws[(s*32 + koct*8 + i)*19 + c];
      acc = __builtin_amdgcn_mfma_f32_16x16x32_bf16(af, bf, acc, 0,0,0);
    }
    __syncthreads();
  }
  #pragma unroll
  for (int j=0; j<4; ++j)
    hW[(size_t)(w*16 + koct*4 + j)*UU + u0 + c] = acc[j];
}

// ---------------- hW (packed-weight variant) ---------------------------------
__global__ __launch_bounds__(256) void hw_mfma_p(
    const u16* __restrict__ hdec, const u16* __restrict__ whpack,
    float* __restrict__ hW)
{
  extern __shared__ char smem[];
  u16* As = (u16*)smem;              // 64 x 1040 B = 66560
  const int tid = threadIdx.x;
  const int l = tid&63, w = tid>>6;
  const int c = l&15, koct = l>>4;
  const int bid = blockIdx.x;
  f32x4 acc = {0.f,0.f,0.f,0.f};
  for (int ch=0; ch<2; ++ch){
    #pragma unroll
    for (int p=0; p<16; ++p){
      int e = p*256 + tid;
      int row = e>>6, k16 = e&63;
      *(short8*)((char*)As + row*1040 + k16*16) =
        *(const short8*)(hdec + (size_t)row*HH + ch*512 + k16*8);
    }
    __syncthreads();
    const u16* wp = whpack + (((size_t)bid*2 + ch)*16)*512;
    #pragma unroll
    for (int s=0; s<16; ++s){
      short8 af = *(const short8*)((const char*)As + (w*16+c)*1040 + s*64 + koct*16);
      short8 bf = *(const short8*)(wp + s*512 + l*8);
      acc = __builtin_amdgcn_mfma_f32_16x16x32_bf16(af, bf, acc, 0,0,0);
    }
    __syncthreads();
  }
  #pragma unroll
  for (int j=0; j<4; ++j)
    hW[(size_t)(w*16 + koct*4 + j)*UU + blockIdx.x*16 + c] = acc[j];
}

// ---------------- scores: e2 = relu( tanh(Eenc + hW) . w2 + b2 ) -------------
__global__ __launch_bounds__(256) void att_scores(
  const u16* __restrict__ eenc, const float* __restrict__ hW,
  const float* __restrict__ w2, const float* __restrict__ b2,
  float* __restrict__ e2)
{
  const int tid = threadIdx.x;
  const int lane = tid & 63;
  const int p = blockIdx.x*4 + (tid>>6);
  const int b = p >> 9;
  const int u0 = lane*8;
  uint4 ev = *reinterpret_cast<const uint4*>(eenc + (size_t)p*UU + u0);
  float4 hw0 = *reinterpret_cast<const float4*>(hW + (size_t)b*UU + u0);
  float4 hw1 = *reinterpret_cast<const float4*>(hW + (size_t)b*UU + u0 + 4);
  float4 w20 = *reinterpret_cast<const float4*>(w2 + u0);
  float4 w21 = *reinterpret_cast<const float4*>(w2 + u0 + 4);
  float sum;
  sum  = tanhfast(bf2f((u16)(ev.x & 0xffff)) + hw0.x) * w20.x;
  sum += tanhfast(bf2f((u16)(ev.x >> 16   )) + hw0.y) * w20.y;
  sum += tanhfast(bf2f((u16)(ev.y & 0xffff)) + hw0.z) * w20.z;
  sum += tanhfast(bf2f((u16)(ev.y >> 16   )) + hw0.w) * w20.w;
  sum += tanhfast(bf2f((u16)(ev.z & 0xffff)) + hw1.x) * w21.x;
  sum += tanhfast(bf2f((u16)(ev.z >> 16   )) + hw1.y) * w21.y;
  sum += tanhfast(bf2f((u16)(ev.w & 0xffff)) + hw1.z) * w21.z;
  sum += tanhfast(bf2f((u16)(ev.w >> 16   )) + hw1.w) * w21.w;
  #pragma unroll
  for (int off=32; off; off>>=1) sum += __shfl_down(sum, off);
  if (lane==0) e2[p] = fmaxf(sum + b2[0], 0.f);
}

// ---------------- softmax over t (in-place on e2) ----------------------------
__global__ __launch_bounds__(256) void att_softmax(
  float* __restrict__ e2, float* __restrict__ outw, int writeOut)
{
  __shared__ float red[256];
  const int b = blockIdx.x, tid = threadIdx.x;
  float v1 = e2[b*TXX + tid], v2 = e2[b*TXX + 256 + tid];
  red[tid] = fmaxf(v1,v2); __syncthreads();
  for (int sft=128; sft; sft>>=1){ if (tid<sft) red[tid] = fmaxf(red[tid], red[tid+sft]); __syncthreads(); }
  float m = red[0]; __syncthreads();
  float x1 = __expf(v1-m), x2 = __expf(v2-m);
  red[tid] = x1+x2; __syncthreads();
  for (int sft=128; sft; sft>>=1){ if (tid<sft) red[tid] += red[tid+sft]; __syncthreads(); }
  float inv = 1.f/red[0];
  float w1v = x1*inv, w2v = x2*inv;
  e2[b*TXX+tid] = w1v; e2[b*TXX+256+tid] = w2v;
  if (writeOut){
    outw[64 + b*TXX + tid] = w1v;
    outw[64 + b*TXX + 256 + tid] = w2v;
  }
}

// ---------------- fused scores + softmax (fallback path) ---------------------
__global__ __launch_bounds__(512) void att_fused(
  const u16* __restrict__ eenc, const float* __restrict__ hW,
  const float* __restrict__ w2, const float* __restrict__ b2v,
  float* __restrict__ wat, float* __restrict__ outw, int writeOut)
{
  __shared__ float sc[512];
  __shared__ float red[512];
  const int tid = threadIdx.x;
  const int l = tid & 63, w = tid >> 6;
  const int b = blockIdx.x;
  const int u0 = l*8;
  float4 hw0 = *(const float4*)(hW + (size_t)b*UU + u0);
  float4 hw1 = *(const float4*)(hW + (size_t)b*UU + u0 + 4);
  float4 w20 = *(const float4*)(w2 + u0);
  float4 w21 = *(const float4*)(w2 + u0 + 4);
  const float bb = b2v[0];
  for (int i=0; i<64; ++i){
    int t = w*64 + i;
    uint4 ev = *(const uint4*)(eenc + ((size_t)b*TXX + t)*UU + u0);
    float sum;
    sum  = tanhfast(bf2f((u16)(ev.x & 0xffff)) + hw0.x) * w20.x;
    sum += tanhfast(bf2f((u16)(ev.x >> 16   )) + hw0.y) * w20.y;
    sum += tanhfast(bf2f((u16)(ev.y & 0xffff)) + hw0.z) * w20.z;
    sum += tanhfast(bf2f((u16)(ev.y >> 16   )) + hw0.w) * w20.w;
    sum += tanhfast(bf2f((u16)(ev.z & 0xffff)) + hw1.x) * w21.x;
    sum += tanhfast(bf2f((u16)(ev.z >> 16   )) + hw1.y) * w21.y;
    sum += tanhfast(bf2f((u16)(ev.w & 0xffff)) + hw1.z) * w21.z;
    sum += tanhfast(bf2f((u16)(ev.w >> 16   )) + hw1.w) * w21.w;
    #pragma unroll
    for (int off=32; off; off>>=1) sum += __shfl_down(sum, off);
    if (l == 0) sc[t] = fmaxf(sum + bb, 0.f);
  }
  __syncthreads();
  float v = sc[tid];
  red[tid] = v;
  __syncthreads();
  for (int s=256; s; s>>=1){ if (tid<s) red[tid] = fmaxf(red[tid], red[tid+s]); __syncthreads(); }
  float m = red[0];
  __syncthreads();
  float ex = __expf(v - m);
  red[tid] = ex;
  __syncthreads();
  for (int s=256; s; s>>=1){ if (tid<s) red[tid] += red[tid+s]; __syncthreads(); }
  float wv = ex / red[0];
  wat[(size_t)b*TXX + tid] = wv;
  if (writeOut) outw[64 + (size_t)b*TXX + tid] = wv;
}

// ---------------- ctx fallback ----------------------------------------------
__global__ __launch_bounds__(512) void ctx_sum(
  const float* __restrict__ e2, const u16* __restrict__ yencT,
  u16* __restrict__ Adec)
{
  extern __shared__ float wl[];
  const int tid = threadIdx.x;
  const int h0 = blockIdx.x*16;
  {
    int b = tid>>3, t0 = (tid&7)*64;
    for (int i=0; i<64; i+=4){
      float4 v = *(const float4*)(e2 + b*TXX + t0 + i);
      wl[(t0+i+0)*65 + b] = v.x; wl[(t0+i+1)*65 + b] = v.y;
      wl[(t0+i+2)*65 + b] = v.z; wl[(t0+i+3)*65 + b] = v.w;
    }
  }
  __syncthreads();
  const int b2 = tid&15, hh = (tid>>4)&15, gg = tid>>8;
  const int g0 = gg*2, g1 = g0+1;
  const int h = h0 + hh;
  float acc0=0.f, acc1=0.f;
  for (int t=0; t<TXX; ++t){
    float w0 = wl[t*65 + g0*16 + b2];
    float w1 = wl[t*65 + g1*16 + b2];
    u16 y0 = yencT[((size_t)(t*4+g0)*1024 + h)*16 + b2];
    u16 y1 = yencT[((size_t)(t*4+g1)*1024 + h)*16 + b2];
    acc0 = fmaf(w0, bf2f(y0), acc0);
    acc1 = fmaf(w1, bf2f(y1), acc1);
  }
  Adec[(size_t)(g0*16+b2)*2080 + 1 + h] = f2bf(acc0);
  Adec[(size_t)(g1*16+b2)*2080 + 1 + h] = f2bf(acc1);
}

// ---------------- ctx two-stage: part over t-chunks --------------------------
__global__ __launch_bounds__(512) void ctx_part(
  const float* __restrict__ wat, const u16* __restrict__ yencT,
  float* __restrict__ part)
{
  extern __shared__ float wl[];      // [64 b][129] f32 chunk = 33024 B
  const int tid = threadIdx.x;
  const int h0 = blockIdx.x*16, tc = blockIdx.y;
  #pragma unroll
  for (int p=0; p<16; ++p){
    int e = p*512 + tid;
    int b = e>>7, tt = e&127;
    wl[b*129 + tt] = wat[(size_t)b*TXX + tc*128 + tt];
  }
  __syncthreads();
  const int b2 = tid&15, hh = (tid>>4)&15, gg = tid>>8;
  const int g0 = gg*2, g1 = g0+1;
  const int h = h0 + hh;
  float acc0=0.f, acc1=0.f;
  #pragma unroll 4
  for (int tt=0; tt<128; ++tt){
    int t = tc*128 + tt;
    float w0 = wl[(g0*16+b2)*129 + tt];
    float w1 = wl[(g1*16+b2)*129 + tt];
    u16 y0 = yencT[((size_t)(t*4+g0)*1024 + h)*16 + b2];
    u16 y1 = yencT[((size_t)(t*4+g1)*1024 + h)*16 + b2];
    acc0 = fmaf(w0, bf2f(y0), acc0);
    acc1 = fmaf(w1, bf2f(y1), acc1);
  }
  part[((size_t)tc*64 + g0*16 + b2)*1024 + h] = acc0;
  part[((size_t)tc*64 + g1*16 + b2)*1024 + h] = acc1;
}

__global__ __launch_bounds__(256) void ctx_red(
  const float* __restrict__ part, u16* __restrict__ Adec)
{
  int idx = blockIdx.x*256 + threadIdx.x;   // 65536 = 64 b x 1024 h
  int b = idx >> 10, h = idx & 1023;
  float s = part[(size_t)b*1024 + h] + part[(size_t)(64+b)*1024 + h]
          + part[(size_t)(128+b)*1024 + h] + part[(size_t)(192+b)*1024 + h];
  Adec[(size_t)b*2080 + 1 + h] = f2bf(s);
}

// ---------------- decoder LSTM fallback --------------------------------------
__global__ __launch_bounds__(256) void dec_mfma(
    const u16* __restrict__ Adec, const float* __restrict__ dec_k_,
    const float* __restrict__ dec_rk_, const float* __restrict__ dec_b_,
    float* __restrict__ cdec, u16* __restrict__ hdec, u16* __restrict__ Anxt)
{
  extern __shared__ char smem[];
  u16* As = (u16*)smem;
  u16* Ws = (u16*)(smem + 54272);
  float* zex = (float*)(smem + 54272 + 15808);
  const int tid = threadIdx.x;
  const int l = tid&63, w = tid>>6;
  const int c = l&15, koct = l>>4;
  const int j0 = blockIdx.x*4;
  const int gcol = (c>>2)*1024 + j0 + (c&3);
  f32x4 acc = {0.f,0.f,0.f,0.f};
  for (int ch=0; ch<5; ++ch){
    for (int p=0; p<13; ++p){
      int e = p*256 + tid;
      int row = e/52, k16 = e - row*52;
      *(short8*)((char*)As + row*848 + k16*16) =
        *(const short8*)(Adec + (size_t)row*2080 + ch*416 + k16*8);
    }
    for (int p=0; p<26; ++p){
      int e = p*256 + tid;
      int kl = e>>4, cc = e&15;
      int kg = ch*416 + kl;
      int col = (cc>>2)*1024 + j0 + (cc&3);
      float v;
      if (kg <= 1024) v = dec_k_[(size_t)kg*G4 + col];
      else if (kg <= 2048) v = dec_rk_[(size_t)(kg-1025)*G4 + col];
      else v = 0.f;
      Ws[kl*19 + cc] = f2bf(v);
    }
    __syncthreads();
    #pragma unroll
    for (int s=0; s<13; ++s){
      short8 af = *(const short8*)((const char*)As + (w*16+c)*848 + s*64 + koct*16);
      short8 bf;
      #pragma unroll
      for (int i=0; i<8; ++i) bf[i] = (short)Ws[(s*32 + koct*8 + i)*19 + c];
      acc = __builtin_amdgcn_mfma_f32_16x16x32_bf16(af, bf, acc, 0,0,0);
    }
    __syncthreads();
  }
  const float sbias = dec_b_[gcol];
  #pragma unroll
  for (int j=0; j<4; ++j)
    zex[(w*16 + koct*4 + j)*17 + c] = acc[j] + sbias;
  __syncthreads();
  {
    int b = tid&63, jj = tid>>6;
    float zi = zex[b*17 + jj], zf = zex[b*17+4+jj], zg = zex[b*17+8+jj], zo = zex[b*17+12+jj];
    float cold = cdec[(j0+jj)*BB + b];
    float cnew = sigm(zf)*cold + sigm(zi)*tanhfast(zg);
    float hnew = sigm(zo)*tanhfast(cnew);
    cdec[(j0+jj)*BB + b] = cnew;
    u16 hb = f2bf(hnew);
    hdec[b*HH + j0 + jj] = hb;
    Anxt[(size_t)b*2080 + 1025 + j0 + jj] = hb;
  }
}

// ---------------- decoder LSTM packed-weight variant (256 blocks x 256 thr) --
__global__ __launch_bounds__(256) void dec_mfma_p(
    const u16* __restrict__ Adec, const u16* __restrict__ wpack,
    const float* __restrict__ dec_b_,
    float* __restrict__ cdec, u16* __restrict__ hdec, u16* __restrict__ Anxt)
{
  extern __shared__ char smem[];
  u16* As = (u16*)smem;                    // 64 x 848 B = 54272
  float* zex = (float*)(smem + 54272);     // 4352
  const int tid = threadIdx.x;
  const int l = tid&63, w = tid>>6;
  const int c = l&15, koct = l>>4;
  const int bid = blockIdx.x;
  const int j0 = bid*4;
  const int gcol = (c>>2)*1024 + j0 + (c&3);
  f32x4 acc = {0.f,0.f,0.f,0.f};
  for (int ch=0; ch<5; ++ch){
    for (int p=0; p<13; ++p){
      int e = p*256 + tid;
      int row = e/52, k16 = e - row*52;
      *(short8*)((char*)As + row*848 + k16*16) =
        *(const short8*)(Adec + (size_t)row*2080 + ch*416 + k16*8);
    }
    __syncthreads();
    const u16* wp = wpack + (((size_t)bid*5 + ch)*13)*512;
    #pragma unroll
    for (int s=0; s<13; ++s){
      short8 af = *(const short8*)((const char*)As + (w*16+c)*848 + s*64 + koct*16);
      short8 bf = *(const short8*)(wp + s*512 + l*8);
      acc = __builtin_amdgcn_mfma_f32_16x16x32_bf16(af, bf, acc, 0,0,0);
    }
    __syncthreads();
  }
  const float sbias = dec_b_[gcol];
  #pragma unroll
  for (int j=0; j<4; ++j)
    zex[(w*16 + koct*4 + j)*17 + c] = acc[j] + sbias;
  __syncthreads();
  {
    int b = tid&63, jj = tid>>6;
    float zi = zex[b*17 + jj], zf = zex[b*17+4+jj], zg = zex[b*17+8+jj], zo = zex[b*17+12+jj];
    float cold = cdec[(j0+jj)*BB + b];
    float cnew = sigm(zf)*cold + sigm(zi)*tanhfast(zg);
    float hnew = sigm(zo)*tanhfast(cnew);
    cdec[(j0+jj)*BB + b] = cnew;
    u16 hb = f2bf(hnew);
    hdec[b*HH + j0 + jj] = hb;
    Anxt[(size_t)b*2080 + 1025 + j0 + jj] = hb;
  }
}

// ---------------- weight pre-pack kernels ------------------------------------
__global__ __launch_bounds__(256) void conv_dec(
  const float* __restrict__ dec_k_, const float* __restrict__ dec_rk_,
  u16* __restrict__ wpack)
{
  const int jb = blockIdx.x;
  for (int e = threadIdx.x; e < 33280; e += 256){
    int i = e & 7, l = (e>>3) & 63;
    int grp = e >> 9;
    int s = grp % 13, ch = grp / 13;
    int c = l & 15, koct = l >> 4;
    int kg = ch*416 + s*32 + koct*8 + i;
    int col = (c>>2)*1024 + jb*4 + (c&3);
    float v;
    if (kg <= 1024) v = dec_k_[(size_t)kg*G4 + col];
    else if (kg <= 2048) v = dec_rk_[(size_t)(kg-1025)*G4 + col];
    else v = 0.f;
    wpack[((((size_t)jb*5 + ch)*13 + s)*64 + l)*8 + i] = f2bf(v);
  }
}

__global__ __launch_bounds__(256) void conv_wh(
  const float* __restrict__ w1, u16* __restrict__ whpack)
{
  const int ub = blockIdx.x;
  for (int e = threadIdx.x; e < 16384; e += 256){
    int i = e & 7, l = (e>>3) & 63;
    int grp = e >> 9;
    int s = grp & 15, ch = grp >> 4;
    int c = l & 15, koct = l >> 4;
    int kg = HH + ch*512 + s*32 + koct*8 + i;
    float v = w1[(size_t)kg*UU + ub*16 + c];
    whpack[((((size_t)ub*2 + ch)*16 + s)*64 + l)*8 + i] = f2bf(v);
  }
}

// ---------------- final y = h @ fin_w + fin_b --------------------------------
__global__ __launch_bounds__(256) void final_y(
  const u16* __restrict__ hdec, const float* __restrict__ fw,
  const float* __restrict__ fb, float* __restrict__ yprev,
  u16* __restrict__ Anxt, float* __restrict__ outy, int writeOut)
{
  __shared__ float red[256];
  const int b = blockIdx.x, tid = threadIdx.x;
  ushort4 hv = *(const ushort4*)(hdec + (size_t)b*HH + tid*4);
  float4 wv = *(const float4*)(fw + tid*4);
  red[tid] = bf2f(hv.x)*wv.x + bf2f(hv.y)*wv.y + bf2f(hv.z)*wv.z + bf2f(hv.w)*wv.w;
  __syncthreads();
  for (int sft=128; sft; sft>>=1){ if (tid<sft) red[tid] += red[tid+sft]; __syncthreads(); }
  if (tid==0){
    float y = red[0] + fb[0];
    yprev[b] = y;
    Anxt[(size_t)b*2080] = f2bf(y);
    if (writeOut) outy[b] = y;
  }
}

__global__ void init_yprev(const float* __restrict__ x, float* __restrict__ yprev,
                           u16* __restrict__ AdecA){
  int b = threadIdx.x;
  if (b < BB){
    float v = x[(size_t)b*TXX*DD + (size_t)(TXX-1)*DD + (DD-1)];
    yprev[b] = v;
    AdecA[(size_t)b*2080] = f2bf(v);
  }
}

__global__ __launch_bounds__(256) void conv_w1(const float* __restrict__ w1, u16* __restrict__ w1b){
  int e = blockIdx.x*256 + threadIdx.x;
  w1b[e] = f2bf(w1[e]);
}

extern "C" void kernel_launch(void* const* d_in, const int* in_sizes, int n_in,
                              void* d_out, int out_size, void* d_ws, size_t ws_size,
                              hipStream_t stream)
{
  (void)in_sizes; (void)n_in; (void)out_size;
  const float* x      = (const float*)d_in[0];
  const float* enc_k  = (const float*)d_in[1];
  const float* enc_rk = (const float*)d_in[2];
  const float* enc_b  = (const float*)d_in[3];
  const float* dec_k  = (const float*)d_in[4];
  const float* dec_rk = (const float*)d_in[5];
  const float* dec_b  = (const float*)d_in[6];
  const float* att_w1 = (const float*)d_in[7];
  const float* att_b1 = (const float*)d_in[8];
  const float* att_w2 = (const float*)d_in[9];
  const float* att_b2 = (const float*)d_in[10];
  const float* fin_w  = (const float*)d_in[11];
  const float* fin_b  = (const float*)d_in[12];
  float* out = (float*)d_out;

  char* wsp = (char*)d_ws;
  u16*   yencT = (u16*)(wsp);                     // 67108864
  u16*   eenc  = (u16*)(wsp + 67108864);          // 33554432
  u16*   w1b   = (u16*)(wsp + 100663296);         // 2097152
  u16*   hdec  = (u16*)(wsp + 102760448);         // 131072
  u16*   AdecA = (u16*)(wsp + 102891520);         // 266240
  u16*   AdecB = (u16*)(wsp + 103157760);         // 266240
  float* cdec  = (float*)(wsp + 103424000);       // 262144
  float* hW    = (float*)(wsp + 103686144);       // 131072
  float* e2    = (float*)(wsp + 103817216);       // 131072 (scores / wat)
  float* yprev = (float*)(wsp + 103948288);       // 256
  unsigned* eflags=(unsigned*)(wsp + 103948544);  // 4096 (unused by 256-blk enc)
  float* part  = (float*)(wsp + 103952640);       // 1048576 (enc flags live here too)
  u16*   whpack= (u16*)(wsp + 105001216);         // 1048576
  u16*   wpack = (u16*)(wsp + 106049792);         // 17039360 -> 123089152
  unsigned* flags = (unsigned*)part;              // 8192 B of part (enc-only lifetime)
  const bool plus = (ws_size >= (size_t)123089152);
  (void)eflags;

  hipFuncSetAttribute((const void*)enc_persist, hipFuncAttributeMaxDynamicSharedMemorySize, 68096);
  hipFuncSetAttribute((const void*)hw_mfma,     hipFuncAttributeMaxDynamicSharedMemorySize, 86016);
  hipFuncSetAttribute((const void*)hw_mfma_p,   hipFuncAttributeMaxDynamicSharedMemorySize, 66560);
  hipFuncSetAttribute((const void*)dec_mfma,    hipFuncAttributeMaxDynamicSharedMemorySize, 74432);
  hipFuncSetAttribute((const void*)dec_mfma_p,  hipFuncAttributeMaxDynamicSharedMemorySize, 58624);
  hipFuncSetAttribute((const void*)ctx_sum,     hipFuncAttributeMaxDynamicSharedMemorySize, 133120);
  hipFuncSetAttribute((const void*)ctx_part,    hipFuncAttributeMaxDynamicSharedMemorySize, 33024);

  hipMemsetAsync(flags, 0, 8192, stream);
  init_yprev<<<1, 64, 0, stream>>>(x, yprev, AdecA);
  conv_w1<<<4096, 256, 0, stream>>>(att_w1, w1b);
  if (plus){
    conv_dec<<<256, 256, 0, stream>>>(dec_k, dec_rk, wpack);
    conv_wh<<<32, 256, 0, stream>>>(att_w1, whpack);
  }

  enc_persist<<<256, 512, 68096, stream>>>(x, enc_k, enc_rk, enc_b, yencT, hdec, cdec, AdecA, flags);

  eenc_mfma<<<dim3(256,8), 256, 0, stream>>>(yencT, w1b, att_b1, eenc);

  for (int s=0; s<TYY; ++s){
    int last = (s == TYY-1);
    u16* Acur = (s&1)? AdecB : AdecA;
    u16* Anxt = (s&1)? AdecA : AdecB;
    if (plus) hw_mfma_p<<<32, 256, 66560, stream>>>(hdec, whpack, hW);
    else      hw_mfma  <<<32, 256, 86016, stream>>>(hdec, w1b, hW);
    if (plus){
      att_scores <<<8192, 256, 0, stream>>>(eenc, hW, att_w2, att_b2, e2);
      att_softmax<<<64, 256, 0, stream>>>(e2, out, last);
      ctx_part<<<dim3(64,4), 512, 33024, stream>>>(e2, yencT, part);
      ctx_red <<<256, 256, 0, stream>>>(part, Acur);
    } else {
      att_fused<<<64, 512, 0, stream>>>(eenc, hW, att_w2, att_b2, e2, out, last);
      ctx_sum <<<64, 512, 133120, stream>>>(e2, yencT, Acur);
    }
    if (plus) dec_mfma_p<<<256, 256, 58624, stream>>>(Acur, wpack, dec_b, cdec, hdec, Anxt);
    else      dec_mfma  <<<256, 256, 74432, stream>>>(Acur, dec_k, dec_rk, dec_b, cdec, hdec, Anxt);
    final_y  <<<64, 256, 0, stream>>>(hdec, fin_w, fin_b, yprev, Anxt, out, last);
  }
}

// Round 18
// 2560.542 us; speedup vs baseline: 1.0101x; 1.0101x over previous
//
#include <hip/hip_runtime.h>

#define BB 64
#define TXX 512
#define DD 64
#define HH 1024
#define UU 512
#define TYY 16
#define G4 4096

using u16 = unsigned short;
typedef __attribute__((ext_vector_type(8))) short short8;
typedef __attribute__((ext_vector_type(4))) float f32x4;

__device__ __forceinline__ float bf2f(u16 v){ return __uint_as_float(((unsigned)v)<<16); }
__device__ __forceinline__ u16 f2bf(float f){
  unsigned u = __float_as_uint(f);
  u += 0x7FFF + ((u>>16)&1);
  return (u16)(u>>16);
}
__device__ __forceinline__ float sigm(float x){
  x = fminf(fmaxf(x,-30.f),30.f);
  return 1.f/(1.f+__expf(-x));
}
__device__ __forceinline__ float tanhfast(float x){
  x = fminf(fmaxf(x,-15.f),15.f);
  float e = __expf(2.f*x);
  return (e-1.f)/(e+1.f);
}

__device__ __forceinline__ unsigned long long tr16(unsigned addr){
  unsigned long long r;
  asm volatile("ds_read_b64_tr_b16 %0, %1" : "=v"(r) : "v"(addr));
  return r;
}

// LLC-coherent (cross-XCD) accesses: sc0 sc1 bypass L1/L2
__device__ __forceinline__ short8 load16_sc(const short8* p){
  short8 r;
  asm volatile("global_load_dwordx4 %0, %1, off sc0 sc1" : "=v"(r) : "v"(p) : "memory");
  return r;
}
__device__ __forceinline__ void store16_sc(void* p, short8 v){
  asm volatile("global_store_dwordx4 %0, %1, off sc0 sc1" :: "v"(p), "v"(v) : "memory");
}

// ---------------- persistent encoder (256 blocks, flag dataflow) -------------
// 256 blocks = 4 b-groups x 64 z-groups (16 h-cols each); 512 thr = 8 waves
// (K slice 128 each). h exchange via yencT (sc0sc1), relaxed per-producer
// flags; consumer wave polls its 8 producers. (r16 session-best, final)
__global__ __launch_bounds__(512, 2) void enc_persist(
    const float* __restrict__ x, const float* __restrict__ enc_k_,
    const float* __restrict__ enc_rk_, const float* __restrict__ enc_b_,
    u16* __restrict__ yencT, u16* __restrict__ hdec,
    float* __restrict__ cdec, u16* __restrict__ AdecA, unsigned* __restrict__ flags)
{
  extern __shared__ char smem[];
  float* zex = (float*)(smem + 32768);            // 8 x 1088 floats = 34816 B
  u16* hbou = (u16*)(smem + 32768 + 34816);       // 512 B
  const int tid = threadIdx.x, bid = blockIdx.x;
  const int l = tid & 63, w = tid >> 6;
  const int c = l & 15, koct = l >> 4;
  const int bg = bid & 3;
  const int zg = bid >> 2;                        // 0..63, 16 h-cols each

  short8 bR[16];
  #pragma unroll
  for (int kk=0; kk<4; ++kk){
    #pragma unroll
    for (int nt=0; nt<4; ++nt){
      short8 f;
      #pragma unroll
      for (int i=0; i<8; ++i){
        int k = w*128 + kk*32 + ((i<4) ? (koct*4+i) : (16 + koct*4 + (i-4)));
        int gcol = nt*1024 + zg*16 + c;
        f[i] = (short)f2bf(enc_rk_[(size_t)k*G4 + gcol]);
      }
      bR[kk*4+nt] = f;
    }
  }
  short8 bK[4];
  if (w < 2){
    #pragma unroll
    for (int nt=0; nt<4; ++nt){
      short8 f;
      #pragma unroll
      for (int i=0; i<8; ++i){
        int gcol = nt*1024 + zg*16 + c;
        f[i] = (short)f2bf(enc_k_[(size_t)(w*32 + koct*8 + i)*G4 + gcol]);
      }
      bK[nt] = f;
    }
  }
  const int gb = (tid >> 4) & 15, ghc = tid & 15;  // gate thread (tid<256)
  float bz[4];
  #pragma unroll
  for (int g4=0; g4<4; ++g4) bz[g4] = enc_b_[g4*1024 + zg*16 + ghc];
  float creg = 0.f;

  const unsigned ldsbase = (unsigned)(size_t)(void*)smem;

  for (int t=0; t<TXX; ++t){
    f32x4 acc[4];
    #pragma unroll
    for (int nt=0; nt<4; ++nt) acc[nt] = (f32x4){0.f,0.f,0.f,0.f};
    if (w < 2){
      const float* xp = x + (size_t)(bg*16 + c)*(TXX*DD) + (size_t)t*DD + w*32 + koct*8;
      float4 v0 = *(const float4*)(xp);
      float4 v1 = *(const float4*)(xp+4);
      short8 ax;
      ax[0]=(short)f2bf(v0.x); ax[1]=(short)f2bf(v0.y);
      ax[2]=(short)f2bf(v0.z); ax[3]=(short)f2bf(v0.w);
      ax[4]=(short)f2bf(v1.x); ax[5]=(short)f2bf(v1.y);
      ax[6]=(short)f2bf(v1.z); ax[7]=(short)f2bf(v1.w);
      #pragma unroll
      for (int nt=0; nt<4; ++nt)
        acc[nt] = __builtin_amdgcn_mfma_f32_16x16x32_bf16(ax, bK[nt], acc[nt], 0,0,0);
    }
    if (t > 0){
      // poll this wave's 8 producers (zg = w*8 .. w*8+7 of same bg)
      if (l < 8){
        const unsigned* fp = flags + ((w*8 + l)*4 + bg)*8;
        while (__hip_atomic_load(fp, __ATOMIC_RELAXED, __HIP_MEMORY_SCOPE_AGENT) < (unsigned)t)
          __builtin_amdgcn_s_sleep(1);
      }
      __builtin_amdgcn_sched_barrier(0);
      const short8* src = (const short8*)(yencT + ((size_t)((t-1)*4 + bg))*16384 + w*2048);
      short8 v0 = load16_sc(src + 0*64 + l);
      short8 v1 = load16_sc(src + 1*64 + l);
      short8 v2 = load16_sc(src + 2*64 + l);
      short8 v3 = load16_sc(src + 3*64 + l);
      asm volatile("s_waitcnt vmcnt(0)" ::: "memory");
      short8* dst = (short8*)(smem + w*4096);
      dst[0*64+l]=v0; dst[1*64+l]=v1; dst[2*64+l]=v2; dst[3*64+l]=v3;
      asm volatile("s_waitcnt lgkmcnt(0)" ::: "memory");
      unsigned a = ldsbase + (unsigned)(w*4096 + l*8);
      unsigned long long r0,r1,r2,r3,r4,r5,r6,r7;
      r0=tr16(a);      r1=tr16(a+512);
      r2=tr16(a+1024); r3=tr16(a+1536);
      r4=tr16(a+2048); r5=tr16(a+2560);
      r6=tr16(a+3072); r7=tr16(a+3584);
      asm volatile("s_waitcnt lgkmcnt(0)" ::: "memory");
      __builtin_amdgcn_sched_barrier(0);
      union { unsigned long long q[2]; short8 s; } u;
      u.q[0]=r0; u.q[1]=r1;
      #pragma unroll
      for (int nt=0; nt<4; ++nt) acc[nt] = __builtin_amdgcn_mfma_f32_16x16x32_bf16(u.s, bR[0+nt], acc[nt], 0,0,0);
      u.q[0]=r2; u.q[1]=r3;
      #pragma unroll
      for (int nt=0; nt<4; ++nt) acc[nt] = __builtin_amdgcn_mfma_f32_16x16x32_bf16(u.s, bR[4+nt], acc[nt], 0,0,0);
      u.q[0]=r4; u.q[1]=r5;
      #pragma unroll
      for (int nt=0; nt<4; ++nt) acc[nt] = __builtin_amdgcn_mfma_f32_16x16x32_bf16(u.s, bR[8+nt], acc[nt], 0,0,0);
      u.q[0]=r6; u.q[1]=r7;
      #pragma unroll
      for (int nt=0; nt<4; ++nt) acc[nt] = __builtin_amdgcn_mfma_f32_16x16x32_bf16(u.s, bR[12+nt], acc[nt], 0,0,0);
    }
    #pragma unroll
    for (int nt=0; nt<4; ++nt){
      #pragma unroll
      for (int j=0; j<4; ++j)
        zex[w*1088 + (koct*4+j)*68 + nt*16 + c] = acc[nt][j];
    }
    __syncthreads();
    if (tid < 256){
      float zsum[4];
      #pragma unroll
      for (int g4=0; g4<4; ++g4){
        float s2 = zex[gb*68 + g4*16 + ghc];
        #pragma unroll
        for (int ww=1; ww<8; ++ww) s2 += zex[ww*1088 + gb*68 + g4*16 + ghc];
        zsum[g4] = s2 + bz[g4];
      }
      float cnew = sigm(zsum[1])*creg + sigm(zsum[0])*tanhfast(zsum[2]);
      float hnew = sigm(zsum[3])*tanhfast(cnew);
      creg = cnew;
      u16 hb = f2bf(hnew);
      hbou[ghc*16 + gb] = hb;
      if (t == TXX-1){
        int bglob = bg*16 + gb;
        int col = zg*16 + ghc;
        hdec[(size_t)bglob*HH + col] = hb;
        cdec[(size_t)col*BB + bglob] = cnew;
        AdecA[(size_t)bglob*2080 + 1025 + col] = hb;
      }
    }
    __syncthreads();   // hbou complete
    if (tid < 32){
      short8 hv = *(const short8*)(hbou + tid*8);
      store16_sc(yencT + ((size_t)(t*4 + bg)*1024 + zg*16)*16 + tid*8, hv);
    }
    asm volatile("s_waitcnt vmcnt(0)" ::: "memory");
    if (tid == 0)
      __hip_atomic_store(flags + (zg*4 + bg)*8, (unsigned)(t+1),
                         __ATOMIC_RELAXED, __HIP_MEMORY_SCOPE_AGENT);
  }
}

// ---------------- Eenc = y_enc @ w1b[:H] + b1 (bf16 out, MFMA) ---------------
__global__ __launch_bounds__(256) void eenc_mfma(
    const u16* __restrict__ yencT, const u16* __restrict__ w1b,
    const float* __restrict__ b1, u16* __restrict__ eenc)
{
  __shared__ u16 As[4096];
  __shared__ u16 Bs[64*40];
  const int tid = threadIdx.x;
  const int l = tid&63, wm = tid>>6;
  const int c = l&15, koct = l>>4;
  const int t0 = blockIdx.x*2, n0 = blockIdx.y*64;
  const unsigned ab = (unsigned)(size_t)(void*)As;
  f32x4 acc[2][4];
  #pragma unroll
  for (int a=0;a<2;++a)
    #pragma unroll
    for (int b=0;b<4;++b) acc[a][b] = (f32x4){0.f,0.f,0.f,0.f};

  for (int k0=0; k0<HH; k0+=32){
    #pragma unroll
    for (int p=0; p<2; ++p){
      int e = p*256 + tid;
      int sub = e>>6, w16 = e&63;
      const u16* gsrc = yencT + ((size_t)((t0 + (sub>>2))*4 + (sub&3))*1024 + k0)*16 + w16*8;
      *(short8*)((char*)As + e*16) = *(const short8*)gsrc;
    }
    #pragma unroll
    for (int p=0; p<8; ++p){
      int e = p*256 + tid;
      int kk = e>>6, col = e&63;
      int k2 = kk & 15;
      int slot = (k2>>2)*8 + ((kk&16)?4:0) + (k2&3);
      Bs[col*40 + slot] = w1b[(size_t)(k0+kk)*UU + n0 + col];
    }
    __syncthreads();
    unsigned long long r00 = tr16(ab + wm*1024 + l*8);
    unsigned long long r01 = tr16(ab + wm*1024 + 512 + l*8);
    unsigned long long r10 = tr16(ab + (wm+4)*1024 + l*8);
    unsigned long long r11 = tr16(ab + (wm+4)*1024 + 512 + l*8);
    asm volatile("s_waitcnt lgkmcnt(0)" ::: "memory");
    __builtin_amdgcn_sched_barrier(0);
    union { unsigned long long q[2]; short8 s; } u0, u1;
    u0.q[0]=r00; u0.q[1]=r01;
    u1.q[0]=r10; u1.q[1]=r11;
    #pragma unroll
    for (int nt=0; nt<4; ++nt){
      short8 bf = *(const short8*)((const char*)Bs + (nt*16+c)*80 + koct*16);
      acc[0][nt] = __builtin_amdgcn_mfma_f32_16x16x32_bf16(u0.s, bf, acc[0][nt], 0,0,0);
      acc[1][nt] = __builtin_amdgcn_mfma_f32_16x16x32_bf16(u1.s, bf, acc[1][nt], 0,0,0);
    }
    __syncthreads();
  }
  float sbn[4];
  #pragma unroll
  for (int nt=0; nt<4; ++nt) sbn[nt] = b1[n0 + nt*16 + c];
  #pragma unroll
  for (int s=0; s<2; ++s){
    int sub = wm + s*4;
    int t = t0 + (sub>>2), g = sub&3;
    #pragma unroll
    for (int nt=0; nt<4; ++nt){
      #pragma unroll
      for (int j=0; j<4; ++j){
        int b = g*16 + koct*4 + j;
        eenc[((size_t)b*TXX + t)*UU + n0 + nt*16 + c] = f2bf(acc[s][nt][j] + sbn[nt]);
      }
    }
  }
}

// ---------------- hW = h @ w1b[H:] (fallback, LDS gather) --------------------
__global__ __launch_bounds__(256) void hw_mfma(
    const u16* __restrict__ hdec, const u16* __restrict__ w1b,
    float* __restrict__ hW)
{
  extern __shared__ char smem[];
  u16* As = (u16*)smem;
  u16* Ws = (u16*)(smem + 66560);
  const int tid = threadIdx.x;
  const int l = tid&63, w = tid>>6;
  const int c = l&15, koct = l>>4;
  const int u0 = blockIdx.x*16;
  f32x4 acc = {0.f,0.f,0.f,0.f};
  for (int ch=0; ch<2; ++ch){
    #pragma unroll
    for (int p=0; p<16; ++p){
      int e = p*256 + tid;
      int row = e>>6, k16 = e&63;
      *(short8*)((char*)As + row*1040 + k16*16) =
        *(const short8*)(hdec + (size_t)row*HH + ch*512 + k16*8);
    }
    #pragma unroll
    for (int p=0; p<32; ++p){
      int e = p*256 + tid;
      int kk = e>>4, cc = e&15;
      Ws[kk*19 + cc] = w1b[(size_t)(HH + ch*512 + kk)*UU + u0 + cc];
    }
    __syncthreads();
    #pragma unroll
    for (int s=0; s<16; ++s){
      short8 af = *(const short8*)((const char*)As + (w*16+c)*1040 + s*64 + koct*16);
      short8 bf;
      #pragma unroll
      for (int i=0; i<8; ++i) bf[i] = (short)Ws[(s*32 + koct*8 + i)*19 + c];
      acc = __builtin_amdgcn_mfma_f32_16x16x32_bf16(af, bf, acc, 0,0,0);
    }
    __syncthreads();
  }
  #pragma unroll
  for (int j=0; j<4; ++j)
    hW[(size_t)(w*16 + koct*4 + j)*UU + u0 + c] = acc[j];
}

// ---------------- hW (packed-weight variant) ---------------------------------
__global__ __launch_bounds__(256) void hw_mfma_p(
    const u16* __restrict__ hdec, const u16* __restrict__ whpack,
    float* __restrict__ hW)
{
  extern __shared__ char smem[];
  u16* As = (u16*)smem;              // 64 x 1040 B = 66560
  const int tid = threadIdx.x;
  const int l = tid&63, w = tid>>6;
  const int c = l&15, koct = l>>4;
  const int bid = blockIdx.x;
  f32x4 acc = {0.f,0.f,0.f,0.f};
  for (int ch=0; ch<2; ++ch){
    #pragma unroll
    for (int p=0; p<16; ++p){
      int e = p*256 + tid;
      int row = e>>6, k16 = e&63;
      *(short8*)((char*)As + row*1040 + k16*16) =
        *(const short8*)(hdec + (size_t)row*HH + ch*512 + k16*8);
    }
    __syncthreads();
    const u16* wp = whpack + (((size_t)bid*2 + ch)*16)*512;
    #pragma unroll
    for (int s=0; s<16; ++s){
      short8 af = *(const short8*)((const char*)As + (w*16+c)*1040 + s*64 + koct*16);
      short8 bf = *(const short8*)(wp + s*512 + l*8);
      acc = __builtin_amdgcn_mfma_f32_16x16x32_bf16(af, bf, acc, 0,0,0);
    }
    __syncthreads();
  }
  #pragma unroll
  for (int j=0; j<4; ++j)
    hW[(size_t)(w*16 + koct*4 + j)*UU + blockIdx.x*16 + c] = acc[j];
}

// ---------------- scores: e2 = relu( tanh(Eenc + hW) . w2 + b2 ) -------------
__global__ __launch_bounds__(256) void att_scores(
  const u16* __restrict__ eenc, const float* __restrict__ hW,
  const float* __restrict__ w2, const float* __restrict__ b2,
  float* __restrict__ e2)
{
  const int tid = threadIdx.x;
  const int lane = tid & 63;
  const int p = blockIdx.x*4 + (tid>>6);
  const int b = p >> 9;
  const int u0 = lane*8;
  uint4 ev = *reinterpret_cast<const uint4*>(eenc + (size_t)p*UU + u0);
  float4 hw0 = *reinterpret_cast<const float4*>(hW + (size_t)b*UU + u0);
  float4 hw1 = *reinterpret_cast<const float4*>(hW + (size_t)b*UU + u0 + 4);
  float4 w20 = *reinterpret_cast<const float4*>(w2 + u0);
  float4 w21 = *reinterpret_cast<const float4*>(w2 + u0 + 4);
  float sum;
  sum  = tanhfast(bf2f((u16)(ev.x & 0xffff)) + hw0.x) * w20.x;
  sum += tanhfast(bf2f((u16)(ev.x >> 16   )) + hw0.y) * w20.y;
  sum += tanhfast(bf2f((u16)(ev.y & 0xffff)) + hw0.z) * w20.z;
  sum += tanhfast(bf2f((u16)(ev.y >> 16   )) + hw0.w) * w20.w;
  sum += tanhfast(bf2f((u16)(ev.z & 0xffff)) + hw1.x) * w21.x;
  sum += tanhfast(bf2f((u16)(ev.z >> 16   )) + hw1.y) * w21.y;
  sum += tanhfast(bf2f((u16)(ev.w & 0xffff)) + hw1.z) * w21.z;
  sum += tanhfast(bf2f((u16)(ev.w >> 16   )) + hw1.w) * w21.w;
  #pragma unroll
  for (int off=32; off; off>>=1) sum += __shfl_down(sum, off);
  if (lane==0) e2[p] = fmaxf(sum + b2[0], 0.f);
}

// ---------------- softmax over t (in-place on e2) ----------------------------
__global__ __launch_bounds__(256) void att_softmax(
  float* __restrict__ e2, float* __restrict__ outw, int writeOut)
{
  __shared__ float red[256];
  const int b = blockIdx.x, tid = threadIdx.x;
  float v1 = e2[b*TXX + tid], v2 = e2[b*TXX + 256 + tid];
  red[tid] = fmaxf(v1,v2); __syncthreads();
  for (int sft=128; sft; sft>>=1){ if (tid<sft) red[tid] = fmaxf(red[tid], red[tid+sft]); __syncthreads(); }
  float m = red[0]; __syncthreads();
  float x1 = __expf(v1-m), x2 = __expf(v2-m);
  red[tid] = x1+x2; __syncthreads();
  for (int sft=128; sft; sft>>=1){ if (tid<sft) red[tid] += red[tid+sft]; __syncthreads(); }
  float inv = 1.f/red[0];
  float w1v = x1*inv, w2v = x2*inv;
  e2[b*TXX+tid] = w1v; e2[b*TXX+256+tid] = w2v;
  if (writeOut){
    outw[64 + b*TXX + tid] = w1v;
    outw[64 + b*TXX + 256 + tid] = w2v;
  }
}

// ---------------- fused scores + softmax (fallback path) ---------------------
__global__ __launch_bounds__(512) void att_fused(
  const u16* __restrict__ eenc, const float* __restrict__ hW,
  const float* __restrict__ w2, const float* __restrict__ b2v,
  float* __restrict__ wat, float* __restrict__ outw, int writeOut)
{
  __shared__ float sc[512];
  __shared__ float red[512];
  const int tid = threadIdx.x;
  const int l = tid & 63, w = tid >> 6;
  const int b = blockIdx.x;
  const int u0 = l*8;
  float4 hw0 = *(const float4*)(hW + (size_t)b*UU + u0);
  float4 hw1 = *(const float4*)(hW + (size_t)b*UU + u0 + 4);
  float4 w20 = *(const float4*)(w2 + u0);
  float4 w21 = *(const float4*)(w2 + u0 + 4);
  const float bb = b2v[0];
  for (int i=0; i<64; ++i){
    int t = w*64 + i;
    uint4 ev = *(const uint4*)(eenc + ((size_t)b*TXX + t)*UU + u0);
    float sum;
    sum  = tanhfast(bf2f((u16)(ev.x & 0xffff)) + hw0.x) * w20.x;
    sum += tanhfast(bf2f((u16)(ev.x >> 16   )) + hw0.y) * w20.y;
    sum += tanhfast(bf2f((u16)(ev.y & 0xffff)) + hw0.z) * w20.z;
    sum += tanhfast(bf2f((u16)(ev.y >> 16   )) + hw0.w) * w20.w;
    sum += tanhfast(bf2f((u16)(ev.z & 0xffff)) + hw1.x) * w21.x;
    sum += tanhfast(bf2f((u16)(ev.z >> 16   )) + hw1.y) * w21.y;
    sum += tanhfast(bf2f((u16)(ev.w & 0xffff)) + hw1.z) * w21.z;
    sum += tanhfast(bf2f((u16)(ev.w >> 16   )) + hw1.w) * w21.w;
    #pragma unroll
    for (int off=32; off; off>>=1) sum += __shfl_down(sum, off);
    if (l == 0) sc[t] = fmaxf(sum + bb, 0.f);
  }
  __syncthreads();
  float v = sc[tid];
  red[tid] = v;
  __syncthreads();
  for (int s=256; s; s>>=1){ if (tid<s) red[tid] = fmaxf(red[tid], red[tid+s]); __syncthreads(); }
  float m = red[0];
  __syncthreads();
  float ex = __expf(v - m);
  red[tid] = ex;
  __syncthreads();
  for (int s=256; s; s>>=1){ if (tid<s) red[tid] += red[tid+s]; __syncthreads(); }
  float wv = ex / red[0];
  wat[(size_t)b*TXX + tid] = wv;
  if (writeOut) outw[64 + (size_t)b*TXX + tid] = wv;
}

// ---------------- ctx fallback ----------------------------------------------
__global__ __launch_bounds__(512) void ctx_sum(
  const float* __restrict__ e2, const u16* __restrict__ yencT,
  u16* __restrict__ Adec)
{
  extern __shared__ float wl[];
  const int tid = threadIdx.x;
  const int h0 = blockIdx.x*16;
  {
    int b = tid>>3, t0 = (tid&7)*64;
    for (int i=0; i<64; i+=4){
      float4 v = *(const float4*)(e2 + b*TXX + t0 + i);
      wl[(t0+i+0)*65 + b] = v.x; wl[(t0+i+1)*65 + b] = v.y;
      wl[(t0+i+2)*65 + b] = v.z; wl[(t0+i+3)*65 + b] = v.w;
    }
  }
  __syncthreads();
  const int b2 = tid&15, hh = (tid>>4)&15, gg = tid>>8;
  const int g0 = gg*2, g1 = g0+1;
  const int h = h0 + hh;
  float acc0=0.f, acc1=0.f;
  for (int t=0; t<TXX; ++t){
    float w0 = wl[t*65 + g0*16 + b2];
    float w1 = wl[t*65 + g1*16 + b2];
    u16 y0 = yencT[((size_t)(t*4+g0)*1024 + h)*16 + b2];
    u16 y1 = yencT[((size_t)(t*4+g1)*1024 + h)*16 + b2];
    acc0 = fmaf(w0, bf2f(y0), acc0);
    acc1 = fmaf(w1, bf2f(y1), acc1);
  }
  Adec[(size_t)(g0*16+b2)*2080 + 1 + h] = f2bf(acc0);
  Adec[(size_t)(g1*16+b2)*2080 + 1 + h] = f2bf(acc1);
}

// ---------------- ctx two-stage: part over t-chunks --------------------------
__global__ __launch_bounds__(512) void ctx_part(
  const float* __restrict__ wat, const u16* __restrict__ yencT,
  float* __restrict__ part)
{
  extern __shared__ float wl[];      // [64 b][129] f32 chunk = 33024 B
  const int tid = threadIdx.x;
  const int h0 = blockIdx.x*16, tc = blockIdx.y;
  #pragma unroll
  for (int p=0; p<16; ++p){
    int e = p*512 + tid;
    int b = e>>7, tt = e&127;
    wl[b*129 + tt] = wat[(size_t)b*TXX + tc*128 + tt];
  }
  __syncthreads();
  const int b2 = tid&15, hh = (tid>>4)&15, gg = tid>>8;
  const int g0 = gg*2, g1 = g0+1;
  const int h = h0 + hh;
  float acc0=0.f, acc1=0.f;
  #pragma unroll 4
  for (int tt=0; tt<128; ++tt){
    int t = tc*128 + tt;
    float w0 = wl[(g0*16+b2)*129 + tt];
    float w1 = wl[(g1*16+b2)*129 + tt];
    u16 y0 = yencT[((size_t)(t*4+g0)*1024 + h)*16 + b2];
    u16 y1 = yencT[((size_t)(t*4+g1)*1024 + h)*16 + b2];
    acc0 = fmaf(w0, bf2f(y0), acc0);
    acc1 = fmaf(w1, bf2f(y1), acc1);
  }
  part[((size_t)tc*64 + g0*16 + b2)*1024 + h] = acc0;
  part[((size_t)tc*64 + g1*16 + b2)*1024 + h] = acc1;
}

__global__ __launch_bounds__(256) void ctx_red(
  const float* __restrict__ part, u16* __restrict__ Adec)
{
  int idx = blockIdx.x*256 + threadIdx.x;   // 65536 = 64 b x 1024 h
  int b = idx >> 10, h = idx & 1023;
  float s = part[(size_t)b*1024 + h] + part[(size_t)(64+b)*1024 + h]
          + part[(size_t)(128+b)*1024 + h] + part[(size_t)(192+b)*1024 + h];
  Adec[(size_t)b*2080 + 1 + h] = f2bf(s);
}

// ---------------- decoder LSTM fallback --------------------------------------
__global__ __launch_bounds__(256) void dec_mfma(
    const u16* __restrict__ Adec, const float* __restrict__ dec_k_,
    const float* __restrict__ dec_rk_, const float* __restrict__ dec_b_,
    float* __restrict__ cdec, u16* __restrict__ hdec, u16* __restrict__ Anxt)
{
  extern __shared__ char smem[];
  u16* As = (u16*)smem;
  u16* Ws = (u16*)(smem + 54272);
  float* zex = (float*)(smem + 54272 + 15808);
  const int tid = threadIdx.x;
  const int l = tid&63, w = tid>>6;
  const int c = l&15, koct = l>>4;
  const int j0 = blockIdx.x*4;
  const int gcol = (c>>2)*1024 + j0 + (c&3);
  f32x4 acc = {0.f,0.f,0.f,0.f};
  for (int ch=0; ch<5; ++ch){
    for (int p=0; p<13; ++p){
      int e = p*256 + tid;
      int row = e/52, k16 = e - row*52;
      *(short8*)((char*)As + row*848 + k16*16) =
        *(const short8*)(Adec + (size_t)row*2080 + ch*416 + k16*8);
    }
    for (int p=0; p<26; ++p){
      int e = p*256 + tid;
      int kl = e>>4, cc = e&15;
      int kg = ch*416 + kl;
      int col = (cc>>2)*1024 + j0 + (cc&3);
      float v;
      if (kg <= 1024) v = dec_k_[(size_t)kg*G4 + col];
      else if (kg <= 2048) v = dec_rk_[(size_t)(kg-1025)*G4 + col];
      else v = 0.f;
      Ws[kl*19 + cc] = f2bf(v);
    }
    __syncthreads();
    #pragma unroll
    for (int s=0; s<13; ++s){
      short8 af = *(const short8*)((const char*)As + (w*16+c)*848 + s*64 + koct*16);
      short8 bf;
      #pragma unroll
      for (int i=0; i<8; ++i) bf[i] = (short)Ws[(s*32 + koct*8 + i)*19 + c];
      acc = __builtin_amdgcn_mfma_f32_16x16x32_bf16(af, bf, acc, 0,0,0);
    }
    __syncthreads();
  }
  const float sbias = dec_b_[gcol];
  #pragma unroll
  for (int j=0; j<4; ++j)
    zex[(w*16 + koct*4 + j)*17 + c] = acc[j] + sbias;
  __syncthreads();
  {
    int b = tid&63, jj = tid>>6;
    float zi = zex[b*17 + jj], zf = zex[b*17+4+jj], zg = zex[b*17+8+jj], zo = zex[b*17+12+jj];
    float cold = cdec[(j0+jj)*BB + b];
    float cnew = sigm(zf)*cold + sigm(zi)*tanhfast(zg);
    float hnew = sigm(zo)*tanhfast(cnew);
    cdec[(j0+jj)*BB + b] = cnew;
    u16 hb = f2bf(hnew);
    hdec[b*HH + j0 + jj] = hb;
    Anxt[(size_t)b*2080 + 1025 + j0 + jj] = hb;
  }
}

// ---------------- decoder LSTM packed-weight variant (256 blocks x 256 thr) --
__global__ __launch_bounds__(256) void dec_mfma_p(
    const u16* __restrict__ Adec, const u16* __restrict__ wpack,
    const float* __restrict__ dec_b_,
    float* __restrict__ cdec, u16* __restrict__ hdec, u16* __restrict__ Anxt)
{
  extern __shared__ char smem[];
  u16* As = (u16*)smem;                    // 64 x 848 B = 54272
  float* zex = (float*)(smem + 54272);     // 4352
  const int tid = threadIdx.x;
  const int l = tid&63, w = tid>>6;
  const int c = l&15, koct = l>>4;
  const int bid = blockIdx.x;
  const int j0 = bid*4;
  const int gcol = (c>>2)*1024 + j0 + (c&3);
  f32x4 acc = {0.f,0.f,0.f,0.f};
  for (int ch=0; ch<5; ++ch){
    for (int p=0; p<13; ++p){
      int e = p*256 + tid;
      int row = e/52, k16 = e - row*52;
      *(short8*)((char*)As + row*848 + k16*16) =
        *(const short8*)(Adec + (size_t)row*2080 + ch*416 + k16*8);
    }
    __syncthreads();
    const u16* wp = wpack + (((size_t)bid*5 + ch)*13)*512;
    #pragma unroll
    for (int s=0; s<13; ++s){
      short8 af = *(const short8*)((const char*)As + (w*16+c)*848 + s*64 + koct*16);
      short8 bf = *(const short8*)(wp + s*512 + l*8);
      acc = __builtin_amdgcn_mfma_f32_16x16x32_bf16(af, bf, acc, 0,0,0);
    }
    __syncthreads();
  }
  const float sbias = dec_b_[gcol];
  #pragma unroll
  for (int j=0; j<4; ++j)
    zex[(w*16 + koct*4 + j)*17 + c] = acc[j] + sbias;
  __syncthreads();
  {
    int b = tid&63, jj = tid>>6;
    float zi = zex[b*17 + jj], zf = zex[b*17+4+jj], zg = zex[b*17+8+jj], zo = zex[b*17+12+jj];
    float cold = cdec[(j0+jj)*BB + b];
    float cnew = sigm(zf)*cold + sigm(zi)*tanhfast(zg);
    float hnew = sigm(zo)*tanhfast(cnew);
    cdec[(j0+jj)*BB + b] = cnew;
    u16 hb = f2bf(hnew);
    hdec[b*HH + j0 + jj] = hb;
    Anxt[(size_t)b*2080 + 1025 + j0 + jj] = hb;
  }
}

// ---------------- weight pre-pack kernels ------------------------------------
__global__ __launch_bounds__(256) void conv_dec(
  const float* __restrict__ dec_k_, const float* __restrict__ dec_rk_,
  u16* __restrict__ wpack)
{
  const int jb = blockIdx.x;
  for (int e = threadIdx.x; e < 33280; e += 256){
    int i = e & 7, l = (e>>3) & 63;
    int grp = e >> 9;
    int s = grp % 13, ch = grp / 13;
    int c = l & 15, koct = l >> 4;
    int kg = ch*416 + s*32 + koct*8 + i;
    int col = (c>>2)*1024 + jb*4 + (c&3);
    float v;
    if (kg <= 1024) v = dec_k_[(size_t)kg*G4 + col];
    else if (kg <= 2048) v = dec_rk_[(size_t)(kg-1025)*G4 + col];
    else v = 0.f;
    wpack[((((size_t)jb*5 + ch)*13 + s)*64 + l)*8 + i] = f2bf(v);
  }
}

__global__ __launch_bounds__(256) void conv_wh(
  const float* __restrict__ w1, u16* __restrict__ whpack)
{
  const int ub = blockIdx.x;
  for (int e = threadIdx.x; e < 16384; e += 256){
    int i = e & 7, l = (e>>3) & 63;
    int grp = e >> 9;
    int s = grp & 15, ch = grp >> 4;
    int c = l & 15, koct = l >> 4;
    int kg = HH + ch*512 + s*32 + koct*8 + i;
    float v = w1[(size_t)kg*UU + ub*16 + c];
    whpack[((((size_t)ub*2 + ch)*16 + s)*64 + l)*8 + i] = f2bf(v);
  }
}

// ---------------- final y = h @ fin_w + fin_b --------------------------------
__global__ __launch_bounds__(256) void final_y(
  const u16* __restrict__ hdec, const float* __restrict__ fw,
  const float* __restrict__ fb, float* __restrict__ yprev,
  u16* __restrict__ Anxt, float* __restrict__ outy, int writeOut)
{
  __shared__ float red[256];
  const int b = blockIdx.x, tid = threadIdx.x;
  ushort4 hv = *(const ushort4*)(hdec + (size_t)b*HH + tid*4);
  float4 wv = *(const float4*)(fw + tid*4);
  red[tid] = bf2f(hv.x)*wv.x + bf2f(hv.y)*wv.y + bf2f(hv.z)*wv.z + bf2f(hv.w)*wv.w;
  __syncthreads();
  for (int sft=128; sft; sft>>=1){ if (tid<sft) red[tid] += red[tid+sft]; __syncthreads(); }
  if (tid==0){
    float y = red[0] + fb[0];
    yprev[b] = y;
    Anxt[(size_t)b*2080] = f2bf(y);
    if (writeOut) outy[b] = y;
  }
}

__global__ void init_yprev(const float* __restrict__ x, float* __restrict__ yprev,
                           u16* __restrict__ AdecA){
  int b = threadIdx.x;
  if (b < BB){
    float v = x[(size_t)b*TXX*DD + (size_t)(TXX-1)*DD + (DD-1)];
    yprev[b] = v;
    AdecA[(size_t)b*2080] = f2bf(v);
  }
}

__global__ __launch_bounds__(256) void conv_w1(const float* __restrict__ w1, u16* __restrict__ w1b){
  int e = blockIdx.x*256 + threadIdx.x;
  w1b[e] = f2bf(w1[e]);
}

extern "C" void kernel_launch(void* const* d_in, const int* in_sizes, int n_in,
                              void* d_out, int out_size, void* d_ws, size_t ws_size,
                              hipStream_t stream)
{
  (void)in_sizes; (void)n_in; (void)out_size;
  const float* x      = (const float*)d_in[0];
  const float* enc_k  = (const float*)d_in[1];
  const float* enc_rk = (const float*)d_in[2];
  const float* enc_b  = (const float*)d_in[3];
  const float* dec_k  = (const float*)d_in[4];
  const float* dec_rk = (const float*)d_in[5];
  const float* dec_b  = (const float*)d_in[6];
  const float* att_w1 = (const float*)d_in[7];
  const float* att_b1 = (const float*)d_in[8];
  const float* att_w2 = (const float*)d_in[9];
  const float* att_b2 = (const float*)d_in[10];
  const float* fin_w  = (const float*)d_in[11];
  const float* fin_b  = (const float*)d_in[12];
  float* out = (float*)d_out;

  char* wsp = (char*)d_ws;
  u16*   yencT = (u16*)(wsp);                     // 67108864
  u16*   eenc  = (u16*)(wsp + 67108864);          // 33554432
  u16*   w1b   = (u16*)(wsp + 100663296);         // 2097152
  u16*   hdec  = (u16*)(wsp + 102760448);         // 131072
  u16*   AdecA = (u16*)(wsp + 102891520);         // 266240
  u16*   AdecB = (u16*)(wsp + 103157760);         // 266240
  float* cdec  = (float*)(wsp + 103424000);       // 262144
  float* hW    = (float*)(wsp + 103686144);       // 131072
  float* e2    = (float*)(wsp + 103817216);       // 131072 (scores / wat)
  float* yprev = (float*)(wsp + 103948288);       // 256
  unsigned* eflags=(unsigned*)(wsp + 103948544);  // 4096 (unused by 256-blk enc)
  float* part  = (float*)(wsp + 103952640);       // 1048576 (enc flags live here too)
  u16*   whpack= (u16*)(wsp + 105001216);         // 1048576
  u16*   wpack = (u16*)(wsp + 106049792);         // 17039360 -> 123089152
  unsigned* flags = (unsigned*)part;              // 8192 B of part (enc-only lifetime)
  const bool plus = (ws_size >= (size_t)123089152);
  (void)eflags;

  hipFuncSetAttribute((const void*)enc_persist, hipFuncAttributeMaxDynamicSharedMemorySize, 68096);
  hipFuncSetAttribute((const void*)hw_mfma,     hipFuncAttributeMaxDynamicSharedMemorySize, 86016);
  hipFuncSetAttribute((const void*)hw_mfma_p,   hipFuncAttributeMaxDynamicSharedMemorySize, 66560);
  hipFuncSetAttribute((const void*)dec_mfma,    hipFuncAttributeMaxDynamicSharedMemorySize, 74432);
  hipFuncSetAttribute((const void*)dec_mfma_p,  hipFuncAttributeMaxDynamicSharedMemorySize, 58624);
  hipFuncSetAttribute((const void*)ctx_sum,     hipFuncAttributeMaxDynamicSharedMemorySize, 133120);
  hipFuncSetAttribute((const void*)ctx_part,    hipFuncAttributeMaxDynamicSharedMemorySize, 33024);

  hipMemsetAsync(flags, 0, 8192, stream);
  init_yprev<<<1, 64, 0, stream>>>(x, yprev, AdecA);
  conv_w1<<<4096, 256, 0, stream>>>(att_w1, w1b);
  if (plus){
    conv_dec<<<256, 256, 0, stream>>>(dec_k, dec_rk, wpack);
    conv_wh<<<32, 256, 0, stream>>>(att_w1, whpack);
  }

  enc_persist<<<256, 512, 68096, stream>>>(x, enc_k, enc_rk, enc_b, yencT, hdec, cdec, AdecA, flags);

  eenc_mfma<<<dim3(256,8), 256, 0, stream>>>(yencT, w1b, att_b1, eenc);

  for (int s=0; s<TYY; ++s){
    int last = (s == TYY-1);
    u16* Acur = (s&1)? AdecB : AdecA;
    u16* Anxt = (s&1)? AdecA : AdecB;
    if (plus) hw_mfma_p<<<32, 256, 66560, stream>>>(hdec, whpack, hW);
    else      hw_mfma  <<<32, 256, 86016, stream>>>(hdec, w1b, hW);
    if (plus){
      att_scores <<<8192, 256, 0, stream>>>(eenc, hW, att_w2, att_b2, e2);
      att_softmax<<<64, 256, 0, stream>>>(e2, out, last);
      ctx_part<<<dim3(64,4), 512, 33024, stream>>>(e2, yencT, part);
      ctx_red <<<256, 256, 0, stream>>>(part, Acur);
    } else {
      att_fused<<<64, 512, 0, stream>>>(eenc, hW, att_w2, att_b2, e2, out, last);
      ctx_sum <<<64, 512, 133120, stream>>>(e2, yencT, Acur);
    }
    if (plus) dec_mfma_p<<<256, 256, 58624, stream>>>(Acur, wpack, dec_b, cdec, hdec, Anxt);
    else      dec_mfma  <<<256, 256, 74432, stream>>>(Acur, dec_k, dec_rk, dec_b, cdec, hdec, Anxt);
    final_y  <<<64, 256, 0, stream>>>(hdec, fin_w, fin_b, yprev, Anxt, out, last);
  }
}